// Round 4
// baseline (706.724 us; speedup 1.0000x reference)
//
#include <hip/hip_runtime.h>
#include <hip/hip_cooperative_groups.h>

// GCN: 3 layers, dims 64->64->64->32, N=100000 nodes, E=1600000 edges.
// Round 14 (fix R13 coop launch):
//  - R13 failed with garbage output (absmax 468): hard-coded coop grid=1024
//    likely exceeded resident capacity (merged kernel VGPR>128 -> 2 blocks/CU
//    -> max 512) => hipLaunchCooperativeKernel failed, unchecked, downstream
//    read garbage. Kernel body audited clean (faithful merge of proven phases).
//  - Fix: size grid via hipOccupancyMaxActiveBlocksPerMultiprocessor * numCU
//    (host queries, capture-safe, cached). Grid-stride phases accept any grid.
//  - Fallback: if query reports no residency, enqueue the proven 6-kernel
//    pipeline (R11/R12 form). Path taken is visible in rocprof dispatch names.
//  - Gather kernels unchanged (R11 form, ~2.9TB/s pattern ceiling).

namespace cg = cooperative_groups;

typedef __attribute__((ext_vector_type(8))) _Float16 half8;
typedef __attribute__((ext_vector_type(4))) _Float16 half4;

static inline int cdiv(int a, int b) { return (a + b - 1) / b; }

#define ACHUNK 8192   // edges per hist/scatter chunk (256 thr x 32)
#define MAXNBK 512    // max buckets (N <= 131072)
#define SCAN_CHUNK 1024
#define BCAP 6144     // bucket capacity for LDS sort (mean 4092)
// LDS union: build phase 256*4 + 256*4 + BCAP*4 = 26624 B (max over phases)
#define SMEM_BYTES 26624

// ---- ONE cooperative kernel: hist -> scan(partial,final) -> scatter ->
// build(csr,row_start,dis) -> layer1 GEMM (x @ W1)*dis -> fp16 H.
__global__ __launch_bounds__(256)
void k_csr_gemm(const int* __restrict__ src, const int* __restrict__ dst,
                int* __restrict__ counts_t, int* __restrict__ offsets,
                int* __restrict__ bsum, unsigned* __restrict__ bucketed,
                int* __restrict__ csr_src, int* __restrict__ row_start,
                float* __restrict__ dis, const float* __restrict__ X,
                const float* __restrict__ W1, _Float16* __restrict__ H,
                int NBK, int NBA, int nmat, int nb, int N, int E) {
    cg::grid_group grid = cg::this_grid();
    __shared__ __align__(16) char smem[SMEM_BYTES];
    const int t = threadIdx.x;
    const int nbl = gridDim.x;

    // ---------- P1: per-chunk bucket histogram ----------
    {
        int* cnt = (int*)smem;
        for (int c = blockIdx.x; c < NBA; c += nbl) {
            for (int i = t; i < NBK; i += 256) cnt[i] = 0;
            __syncthreads();
            int e0 = c * ACHUNK;
#pragma unroll 8
            for (int j = 0; j < ACHUNK / 256; ++j) {
                int e = e0 + j * 256 + t;
                if (e < E) atomicAdd(&cnt[dst[e] >> 8], 1);
            }
            __syncthreads();
            for (int i = t; i < NBK; i += 256) counts_t[i * NBA + c] = cnt[i];
            __syncthreads();
        }
    }
    grid.sync();

    // ---------- P2: scan partial (block sums) ----------
    {
        int* red = (int*)smem;
        for (int b = blockIdx.x; b < nb; b += nbl) {
            int base = b * SCAN_CHUNK + t * 4;
            int s = 0;
#pragma unroll
            for (int j = 0; j < 4; ++j) { int i = base + j; if (i < nmat) s += counts_t[i]; }
            red[t] = s;
            __syncthreads();
            for (int off = 128; off > 0; off >>= 1) {
                if (t < off) red[t] += red[t + off];
                __syncthreads();
            }
            if (t == 0) bsum[b] = red[0];
            __syncthreads();
        }
    }
    grid.sync();

    // ---------- P3: scan final (redundant bsum scan per block) ----------
    {
        int* sb = (int*)smem;
        int* sh = sb + 256;
        for (int bk = blockIdx.x; bk < nb; bk += nbl) {
            sb[t] = (t < nb) ? bsum[t] : 0;
            __syncthreads();
            for (int off = 1; off < 256; off <<= 1) {
                int u = (t >= off) ? sb[t - off] : 0;
                __syncthreads();
                sb[t] += u;
                __syncthreads();
            }
            int bbase = (bk == 0) ? 0 : sb[bk - 1];
            int base = bk * SCAN_CHUNK + t * 4;
            int v[4];
            int s = 0;
#pragma unroll
            for (int j = 0; j < 4; ++j) {
                int i = base + j;
                v[j] = (i < nmat) ? counts_t[i] : 0;
                s += v[j];
            }
            sh[t] = s;
            __syncthreads();
            for (int off = 1; off < 256; off <<= 1) {
                int u = (t >= off) ? sh[t - off] : 0;
                __syncthreads();
                sh[t] += u;
                __syncthreads();
            }
            int run = sh[t] - s + bbase;
#pragma unroll
            for (int j = 0; j < 4; ++j) {
                int i = base + j;
                if (i < nmat) { offsets[i] = run; run += v[j]; }
            }
            __syncthreads();
        }
    }
    grid.sync();

    // ---------- P4: scatter edges into bucket regions (LDS cursors) ----------
    {
        int* curs = (int*)smem;
        for (int c = blockIdx.x; c < NBA; c += nbl) {
            for (int i = t; i < NBK; i += 256) curs[i] = offsets[i * NBA + c];
            __syncthreads();
            int e0 = c * ACHUNK;
#pragma unroll 8
            for (int j = 0; j < ACHUNK / 256; ++j) {
                int e = e0 + j * 256 + t;
                if (e < E) {
                    int d = dst[e];
                    int pos = atomicAdd(&curs[d >> 8], 1);
                    bucketed[pos] = (unsigned)src[e] | ((unsigned)(d & 255) << 24);
                }
            }
            __syncthreads();
        }
    }
    grid.sync();

    // ---------- P5: per-bucket build: hist -> scan -> LDS sort -> coalesced
    // csr_src write; row_start, dis ----------
    {
        int* cnt = (int*)smem;
        int* sc  = cnt + 256;
        int* srt = sc + 256;
        for (int k = blockIdx.x; k < NBK; k += nbl) {
            int base = offsets[k * NBA];
            int end = (k + 1 < NBK) ? offsets[(k + 1) * NBA] : E;
            cnt[t] = 0;
            __syncthreads();
            for (int i = base + t; i < end; i += 256)
                atomicAdd(&cnt[bucketed[i] >> 24], 1);
            __syncthreads();
            int c = cnt[t];
            sc[t] = c;
            __syncthreads();
            for (int off = 1; off < 256; off <<= 1) {
                int u = (t >= off) ? sc[t - off] : 0;
                __syncthreads();
                sc[t] += u;
                __syncthreads();
            }
            int excl = sc[t] - c;
            int node = k * 256 + t;
            if (node < N) {
                row_start[node] = base + excl;
                dis[node] = rsqrtf(1.0f + (float)c);
            }
            if (k == 0 && t == 0) row_start[N] = E;
            cnt[t] = excl;  // local cursor
            __syncthreads();
            int m = end - base;
            if (m <= BCAP) {
                for (int i = base + t; i < end; i += 256) {
                    unsigned w = bucketed[i];
                    int r = atomicAdd(&cnt[w >> 24], 1);
                    srt[r] = (int)(w & 0xFFFFFFu);
                }
                __syncthreads();
                for (int idx = t; idx < m; idx += 256)
                    csr_src[base + idx] = srt[idx];
            } else {
                for (int i = base + t; i < end; i += 256) {
                    unsigned w = bucketed[i];
                    int pos = base + atomicAdd(&cnt[w >> 24], 1);
                    csr_src[pos] = (int)(w & 0xFFFFFFu);
                }
            }
            __syncthreads();
        }
    }
    grid.sync();

    // ---------- P6: layer-1 GEMM: H = fp16((X @ W1) * dis[row]) ----------
    {
        float* Ws = (float*)smem;        // 64*64 f32 = 16KB
        float* Xs = Ws + 64 * 64;        // 32*65 f32 = 8.3KB
        constexpr int K = 64, KP = 65;
        // stage W1 once
        for (int idx = t; idx < K * 64 / 4; idx += 256)
            ((float4*)Ws)[idx] = ((const float4*)W1)[idx];
        int ntile = (N + 31) / 32;
        int r = t / 8, c0 = (t % 8) * 8;
        for (int tile = blockIdx.x; tile < ntile; tile += nbl) {
            int row0 = tile * 32;
            for (int idx = t; idx < 32 * (K / 4); idx += 256) {
                int rr = idx / (K / 4), kq = idx % (K / 4);
                int row = row0 + rr;
                float4 vv = (row < N) ? ((const float4*)X)[(size_t)row * (K / 4) + kq]
                                      : make_float4(0.f, 0.f, 0.f, 0.f);
                Xs[rr * KP + kq * 4 + 0] = vv.x;
                Xs[rr * KP + kq * 4 + 1] = vv.y;
                Xs[rr * KP + kq * 4 + 2] = vv.z;
                Xs[rr * KP + kq * 4 + 3] = vv.w;
            }
            __syncthreads();
            int row = row0 + r;
            if (row < N) {
                float4 a0 = make_float4(0.f, 0.f, 0.f, 0.f);
                float4 a1 = make_float4(0.f, 0.f, 0.f, 0.f);
#pragma unroll
                for (int k = 0; k < K; ++k) {
                    float xv = Xs[r * KP + k];
                    float4 w0 = ((const float4*)Ws)[(k * 64 + c0) / 4];
                    float4 w1 = ((const float4*)Ws)[(k * 64 + c0) / 4 + 1];
                    a0.x = fmaf(xv, w0.x, a0.x);
                    a0.y = fmaf(xv, w0.y, a0.y);
                    a0.z = fmaf(xv, w0.z, a0.z);
                    a0.w = fmaf(xv, w0.w, a0.w);
                    a1.x = fmaf(xv, w1.x, a1.x);
                    a1.y = fmaf(xv, w1.y, a1.y);
                    a1.z = fmaf(xv, w1.z, a1.z);
                    a1.w = fmaf(xv, w1.w, a1.w);
                }
                float dn = dis[row];
                half8 hv;
                hv[0] = (_Float16)(a0.x * dn);
                hv[1] = (_Float16)(a0.y * dn);
                hv[2] = (_Float16)(a0.z * dn);
                hv[3] = (_Float16)(a0.w * dn);
                hv[4] = (_Float16)(a1.x * dn);
                hv[5] = (_Float16)(a1.y * dn);
                hv[6] = (_Float16)(a1.z * dn);
                hv[7] = (_Float16)(a1.w * dn);
                ((half8*)H)[(size_t)row * 8 + c0 / 8] = hv;
            }
            __syncthreads();
        }
    }
}

// ================= fallback separate kernels (proven R11/R12 path) =========

__global__ void k_bucket_hist(const int* __restrict__ dst, int* __restrict__ counts_t,
                              int NBK, int NBA, int E) {
    __shared__ int cnt[MAXNBK];
    int t = threadIdx.x, b = blockIdx.x;
    for (int i = t; i < NBK; i += 256) cnt[i] = 0;
    __syncthreads();
    int e0 = b * ACHUNK;
#pragma unroll 8
    for (int j = 0; j < ACHUNK / 256; ++j) {
        int e = e0 + j * 256 + t;
        if (e < E) atomicAdd(&cnt[dst[e] >> 8], 1);
    }
    __syncthreads();
    for (int i = t; i < NBK; i += 256) counts_t[i * NBA + b] = cnt[i];
}

__global__ void k_scan_partial(const int* __restrict__ a, int* __restrict__ bsum, int n) {
    __shared__ int red[256];
    int t = threadIdx.x, b = blockIdx.x;
    int base = b * SCAN_CHUNK + t * 4;
    int s = 0;
#pragma unroll
    for (int j = 0; j < 4; ++j) { int i = base + j; if (i < n) s += a[i]; }
    red[t] = s;
    __syncthreads();
    for (int off = 128; off > 0; off >>= 1) {
        if (t < off) red[t] += red[t + off];
        __syncthreads();
    }
    if (t == 0) bsum[b] = red[0];
}

__global__ void k_scan_final(const int* __restrict__ a, const int* __restrict__ bsum,
                             int* __restrict__ out, int nb, int n) {
    __shared__ int sb[256];
    __shared__ int sh[256];
    int t = threadIdx.x, bk = blockIdx.x;
    sb[t] = (t < nb) ? bsum[t] : 0;
    __syncthreads();
    for (int off = 1; off < 256; off <<= 1) {
        int u = (t >= off) ? sb[t - off] : 0;
        __syncthreads();
        sb[t] += u;
        __syncthreads();
    }
    int bbase = (bk == 0) ? 0 : sb[bk - 1];
    int base = bk * SCAN_CHUNK + t * 4;
    int v[4];
    int s = 0;
#pragma unroll
    for (int j = 0; j < 4; ++j) {
        int i = base + j;
        v[j] = (i < n) ? a[i] : 0;
        s += v[j];
    }
    sh[t] = s;
    __syncthreads();
    for (int off = 1; off < 256; off <<= 1) {
        int u = (t >= off) ? sh[t - off] : 0;
        __syncthreads();
        sh[t] += u;
        __syncthreads();
    }
    int run = sh[t] - s + bbase;
#pragma unroll
    for (int j = 0; j < 4; ++j) {
        int i = base + j;
        if (i < n) { out[i] = run; run += v[j]; }
    }
}

__global__ void k_bucket_scatter(const int* __restrict__ src, const int* __restrict__ dst,
                                 const int* __restrict__ offsets, unsigned* __restrict__ bucketed,
                                 int NBK, int NBA, int E) {
    __shared__ int curs[MAXNBK];
    int t = threadIdx.x, b = blockIdx.x;
    for (int i = t; i < NBK; i += 256) curs[i] = offsets[i * NBA + b];
    __syncthreads();
    int e0 = b * ACHUNK;
#pragma unroll 8
    for (int j = 0; j < ACHUNK / 256; ++j) {
        int e = e0 + j * 256 + t;
        if (e < E) {
            int d = dst[e];
            int pos = atomicAdd(&curs[d >> 8], 1);
            bucketed[pos] = (unsigned)src[e] | ((unsigned)(d & 255) << 24);
        }
    }
}

__global__ void k_bucket_build(const unsigned* __restrict__ bucketed,
                               const int* __restrict__ offsets,
                               int* __restrict__ csr_src, int* __restrict__ row_start,
                               float* __restrict__ dis, int NBK, int NBA, int N, int E) {
    __shared__ int cnt[256];
    __shared__ int sc[256];
    __shared__ int srt[BCAP];
    int t = threadIdx.x, k = blockIdx.x;
    int base = offsets[k * NBA];
    int end = (k + 1 < NBK) ? offsets[(k + 1) * NBA] : E;
    cnt[t] = 0;
    __syncthreads();
    for (int i = base + t; i < end; i += 256)
        atomicAdd(&cnt[bucketed[i] >> 24], 1);
    __syncthreads();
    int c = cnt[t];
    sc[t] = c;
    __syncthreads();
    for (int off = 1; off < 256; off <<= 1) {
        int u = (t >= off) ? sc[t - off] : 0;
        __syncthreads();
        sc[t] += u;
        __syncthreads();
    }
    int excl = sc[t] - c;
    int node = k * 256 + t;
    if (node < N) {
        row_start[node] = base + excl;
        dis[node] = rsqrtf(1.0f + (float)c);
    }
    if (k == 0 && t == 0) row_start[N] = E;
    cnt[t] = excl;
    __syncthreads();
    int m = end - base;
    if (m <= BCAP) {
        for (int i = base + t; i < end; i += 256) {
            unsigned w = bucketed[i];
            int r = atomicAdd(&cnt[w >> 24], 1);
            srt[r] = (int)(w & 0xFFFFFFu);
        }
        __syncthreads();
        for (int idx = t; idx < m; idx += 256)
            csr_src[base + idx] = srt[idx];
    } else {
        for (int i = base + t; i < end; i += 256) {
            unsigned w = bucketed[i];
            int pos = base + atomicAdd(&cnt[w >> 24], 1);
            csr_src[pos] = (int)(w & 0xFFFFFFu);
        }
    }
}

template <int K, int M>
__global__ void k_gemm_f(const float* __restrict__ X, const float* __restrict__ W,
                         const float* __restrict__ dis, _Float16* __restrict__ H, int n) {
    constexpr int TPR = M / 8;
    constexpr int ROWS = 256 / TPR;
    constexpr int KP = K + 1;
    __shared__ float Ws[K * M];
    __shared__ float Xs[ROWS * KP];
    int tid = threadIdx.x;
    for (int idx = tid; idx < K * M / 4; idx += 256)
        ((float4*)Ws)[idx] = ((const float4*)W)[idx];
    int row0 = blockIdx.x * ROWS;
    for (int idx = tid; idx < ROWS * (K / 4); idx += 256) {
        int r = idx / (K / 4), kq = idx % (K / 4);
        int row = row0 + r;
        float4 vv = (row < n) ? ((const float4*)X)[(size_t)row * (K / 4) + kq]
                              : make_float4(0.f, 0.f, 0.f, 0.f);
        Xs[r * KP + kq * 4 + 0] = vv.x;
        Xs[r * KP + kq * 4 + 1] = vv.y;
        Xs[r * KP + kq * 4 + 2] = vv.z;
        Xs[r * KP + kq * 4 + 3] = vv.w;
    }
    __syncthreads();
    int r = tid / TPR, c0 = (tid % TPR) * 8;
    int row = row0 + r;
    if (row >= n) return;
    float4 a0 = make_float4(0.f, 0.f, 0.f, 0.f);
    float4 a1 = make_float4(0.f, 0.f, 0.f, 0.f);
#pragma unroll
    for (int k = 0; k < K; ++k) {
        float xv = Xs[r * KP + k];
        float4 w0 = ((const float4*)Ws)[(k * M + c0) / 4];
        float4 w1 = ((const float4*)Ws)[(k * M + c0) / 4 + 1];
        a0.x = fmaf(xv, w0.x, a0.x);
        a0.y = fmaf(xv, w0.y, a0.y);
        a0.z = fmaf(xv, w0.z, a0.z);
        a0.w = fmaf(xv, w0.w, a0.w);
        a1.x = fmaf(xv, w1.x, a1.x);
        a1.y = fmaf(xv, w1.y, a1.y);
        a1.z = fmaf(xv, w1.z, a1.z);
        a1.w = fmaf(xv, w1.w, a1.w);
    }
    float dn = dis[row];
    half8 hv;
    hv[0] = (_Float16)(a0.x * dn);
    hv[1] = (_Float16)(a0.y * dn);
    hv[2] = (_Float16)(a0.z * dn);
    hv[3] = (_Float16)(a0.w * dn);
    hv[4] = (_Float16)(a1.x * dn);
    hv[5] = (_Float16)(a1.y * dn);
    hv[6] = (_Float16)(a1.z * dn);
    hv[7] = (_Float16)(a1.w * dn);
    ((half8*)H)[(size_t)row * (M / 8) + c0 / 8] = hv;
}

// ================= gather kernels (unchanged, R11 form) =====================

// ---- FUSED: aggregate(64) [+relu] -> LDS -> GEMM(64 x MOUT) -> h' fp16.
template <int MOUT>
__global__ __launch_bounds__(256, 8)
void k_fused_agg_gemm(const _Float16* __restrict__ h, const float* __restrict__ dis,
                      const int* __restrict__ row_start, const int* __restrict__ csr_src,
                      const float* __restrict__ bagg, const float* __restrict__ W,
                      _Float16* __restrict__ H, int n) {
    constexpr int K = 64, KP = K + 1;
    __shared__ __align__(16) _Float16 Ws[K * MOUT];
    __shared__ float Xs[32 * KP];
    int tid = threadIdx.x;
    for (int idx = tid; idx < K * MOUT / 4; idx += 256) {
        float4 wv = ((const float4*)W)[idx];
        half4 h4;
        h4[0] = (_Float16)wv.x;
        h4[1] = (_Float16)wv.y;
        h4[2] = (_Float16)wv.z;
        h4[3] = (_Float16)wv.w;
        ((half4*)Ws)[idx] = h4;
    }

    int wave = tid >> 6, lane = tid & 63;
    int sub = lane >> 3, fl = lane & 7;
    int node0 = blockIdx.x * 32;
    int node = node0 + wave * 8 + sub;
    if (node < n) {
        const half8* h8 = (const half8*)h;
        float acc[8];
#pragma unroll
        for (int j = 0; j < 8; ++j) acc[j] = 0.f;
        int e = row_start[node], e1 = row_start[node + 1];
        for (; e + 7 < e1; e += 8) {
            int s0 = csr_src[e], s1 = csr_src[e + 1];
            int s2 = csr_src[e + 2], s3 = csr_src[e + 3];
            int s4 = csr_src[e + 4], s5 = csr_src[e + 5];
            int s6 = csr_src[e + 6], s7 = csr_src[e + 7];
            half8 v0 = h8[(size_t)s0 * 8 + fl];
            half8 v1 = h8[(size_t)s1 * 8 + fl];
            half8 v2 = h8[(size_t)s2 * 8 + fl];
            half8 v3 = h8[(size_t)s3 * 8 + fl];
            half8 v4 = h8[(size_t)s4 * 8 + fl];
            half8 v5 = h8[(size_t)s5 * 8 + fl];
            half8 v6 = h8[(size_t)s6 * 8 + fl];
            half8 v7 = h8[(size_t)s7 * 8 + fl];
#pragma unroll
            for (int j = 0; j < 8; ++j)
                acc[j] += (((float)v0[j] + (float)v1[j]) + ((float)v2[j] + (float)v3[j])) +
                          (((float)v4[j] + (float)v5[j]) + ((float)v6[j] + (float)v7[j]));
        }
        for (; e + 3 < e1; e += 4) {
            int s0 = csr_src[e], s1 = csr_src[e + 1];
            int s2 = csr_src[e + 2], s3 = csr_src[e + 3];
            half8 v0 = h8[(size_t)s0 * 8 + fl];
            half8 v1 = h8[(size_t)s1 * 8 + fl];
            half8 v2 = h8[(size_t)s2 * 8 + fl];
            half8 v3 = h8[(size_t)s3 * 8 + fl];
#pragma unroll
            for (int j = 0; j < 8; ++j)
                acc[j] += ((float)v0[j] + (float)v1[j]) + ((float)v2[j] + (float)v3[j]);
        }
        for (; e < e1; ++e) {
            int s0 = csr_src[e];
            half8 v0 = h8[(size_t)s0 * 8 + fl];
#pragma unroll
            for (int j = 0; j < 8; ++j) acc[j] += (float)v0[j];
        }
        float dn = dis[node];
        half8 hv = h8[(size_t)node * 8 + fl];
        float4 b0 = ((const float4*)bagg)[fl * 2];
        float4 b1 = ((const float4*)bagg)[fl * 2 + 1];
        int rrow = wave * 8 + sub;
        float* xp = &Xs[rrow * KP + fl * 8];
        xp[0] = fmaxf((acc[0] + (float)hv[0]) * dn + b0.x, 0.f);
        xp[1] = fmaxf((acc[1] + (float)hv[1]) * dn + b0.y, 0.f);
        xp[2] = fmaxf((acc[2] + (float)hv[2]) * dn + b0.z, 0.f);
        xp[3] = fmaxf((acc[3] + (float)hv[3]) * dn + b0.w, 0.f);
        xp[4] = fmaxf((acc[4] + (float)hv[4]) * dn + b1.x, 0.f);
        xp[5] = fmaxf((acc[5] + (float)hv[5]) * dn + b1.y, 0.f);
        xp[6] = fmaxf((acc[6] + (float)hv[6]) * dn + b1.z, 0.f);
        xp[7] = fmaxf((acc[7] + (float)hv[7]) * dn + b1.w, 0.f);
    }
    __syncthreads();

    constexpr int TPR = 8;
    constexpr int CPT = MOUT / TPR;
    int r = tid / TPR, c0 = (tid % TPR) * CPT;
    int row = node0 + r;
    if (row >= n) return;
    float4 a0 = make_float4(0.f, 0.f, 0.f, 0.f);
    float4 a1 = make_float4(0.f, 0.f, 0.f, 0.f);
#pragma unroll
    for (int k = 0; k < K; ++k) {
        float xv = Xs[r * KP + k];
        if constexpr (CPT == 8) {
            half8 w = ((const half8*)Ws)[(k * MOUT + c0) / 8];
            a0.x = fmaf(xv, (float)w[0], a0.x);
            a0.y = fmaf(xv, (float)w[1], a0.y);
            a0.z = fmaf(xv, (float)w[2], a0.z);
            a0.w = fmaf(xv, (float)w[3], a0.w);
            a1.x = fmaf(xv, (float)w[4], a1.x);
            a1.y = fmaf(xv, (float)w[5], a1.y);
            a1.z = fmaf(xv, (float)w[6], a1.z);
            a1.w = fmaf(xv, (float)w[7], a1.w);
        } else {
            half4 w = ((const half4*)Ws)[(k * MOUT + c0) / 4];
            a0.x = fmaf(xv, (float)w[0], a0.x);
            a0.y = fmaf(xv, (float)w[1], a0.y);
            a0.z = fmaf(xv, (float)w[2], a0.z);
            a0.w = fmaf(xv, (float)w[3], a0.w);
        }
    }
    float dn = dis[row];
    if constexpr (CPT == 8) {
        half8 hv;
        hv[0] = (_Float16)(a0.x * dn);
        hv[1] = (_Float16)(a0.y * dn);
        hv[2] = (_Float16)(a0.z * dn);
        hv[3] = (_Float16)(a0.w * dn);
        hv[4] = (_Float16)(a1.x * dn);
        hv[5] = (_Float16)(a1.y * dn);
        hv[6] = (_Float16)(a1.z * dn);
        hv[7] = (_Float16)(a1.w * dn);
        ((half8*)H)[(size_t)row * (MOUT / 8) + c0 / 8] = hv;
    } else {
        half4 hv;
        hv[0] = (_Float16)(a0.x * dn);
        hv[1] = (_Float16)(a0.y * dn);
        hv[2] = (_Float16)(a0.z * dn);
        hv[3] = (_Float16)(a0.w * dn);
        ((half4*)H)[(size_t)row * (MOUT / 4) + c0 / 4] = hv;
    }
}

// ---- final aggregate: M=32, fp32 out, no relu.
__global__ __launch_bounds__(256, 8)
void k_aggregate32(const _Float16* __restrict__ h, const float* __restrict__ dis,
                   const int* __restrict__ row_start, const int* __restrict__ csr_src,
                   const float* __restrict__ b, float* __restrict__ out, int n) {
    constexpr int LPN = 4, NPW = 16;
    int gtid = blockIdx.x * blockDim.x + threadIdx.x;
    int wave = gtid >> 6;
    int lane = threadIdx.x & 63;
    int sub = lane / LPN, fl = lane % LPN;
    int node = wave * NPW + sub;
    if (node >= n) return;
    const half8* h8 = (const half8*)h;
    float acc[8];
#pragma unroll
    for (int j = 0; j < 8; ++j) acc[j] = 0.f;
    int e = row_start[node], e1 = row_start[node + 1];
    for (; e + 7 < e1; e += 8) {
        int s0 = csr_src[e], s1 = csr_src[e + 1];
        int s2 = csr_src[e + 2], s3 = csr_src[e + 3];
        int s4 = csr_src[e + 4], s5 = csr_src[e + 5];
        int s6 = csr_src[e + 6], s7 = csr_src[e + 7];
        half8 v0 = h8[(size_t)s0 * LPN + fl];
        half8 v1 = h8[(size_t)s1 * LPN + fl];
        half8 v2 = h8[(size_t)s2 * LPN + fl];
        half8 v3 = h8[(size_t)s3 * LPN + fl];
        half8 v4 = h8[(size_t)s4 * LPN + fl];
        half8 v5 = h8[(size_t)s5 * LPN + fl];
        half8 v6 = h8[(size_t)s6 * LPN + fl];
        half8 v7 = h8[(size_t)s7 * LPN + fl];
#pragma unroll
        for (int j = 0; j < 8; ++j)
            acc[j] += (((float)v0[j] + (float)v1[j]) + ((float)v2[j] + (float)v3[j])) +
                      (((float)v4[j] + (float)v5[j]) + ((float)v6[j] + (float)v7[j]));
    }
    for (; e + 3 < e1; e += 4) {
        int s0 = csr_src[e], s1 = csr_src[e + 1];
        int s2 = csr_src[e + 2], s3 = csr_src[e + 3];
        half8 v0 = h8[(size_t)s0 * LPN + fl];
        half8 v1 = h8[(size_t)s1 * LPN + fl];
        half8 v2 = h8[(size_t)s2 * LPN + fl];
        half8 v3 = h8[(size_t)s3 * LPN + fl];
#pragma unroll
        for (int j = 0; j < 8; ++j)
            acc[j] += ((float)v0[j] + (float)v1[j]) + ((float)v2[j] + (float)v3[j]);
    }
    for (; e < e1; ++e) {
        int s0 = csr_src[e];
        half8 v0 = h8[(size_t)s0 * LPN + fl];
#pragma unroll
        for (int j = 0; j < 8; ++j) acc[j] += (float)v0[j];
    }
    float dn = dis[node];
    half8 hv = h8[(size_t)node * LPN + fl];
    float4 b0 = ((const float4*)b)[fl * 2];
    float4 b1 = ((const float4*)b)[fl * 2 + 1];
    float4* op = (float4*)(out + ((size_t)node * LPN + fl) * 8);
    op[0] = make_float4((acc[0] + (float)hv[0]) * dn + b0.x,
                        (acc[1] + (float)hv[1]) * dn + b0.y,
                        (acc[2] + (float)hv[2]) * dn + b0.z,
                        (acc[3] + (float)hv[3]) * dn + b0.w);
    op[1] = make_float4((acc[4] + (float)hv[4]) * dn + b1.x,
                        (acc[5] + (float)hv[5]) * dn + b1.y,
                        (acc[6] + (float)hv[6]) * dn + b1.z,
                        (acc[7] + (float)hv[7]) * dn + b1.w);
}

extern "C" void kernel_launch(void* const* d_in, const int* in_sizes, int n_in,
                              void* d_out, int out_size, void* d_ws, size_t ws_size,
                              hipStream_t stream) {
    const float* x   = (const float*)d_in[0];
    const int*   ei  = (const int*)d_in[1];
    const float* W1  = (const float*)d_in[2];
    const float* b1  = (const float*)d_in[3];
    const float* W2  = (const float*)d_in[4];
    const float* b2  = (const float*)d_in[5];
    const float* W3  = (const float*)d_in[6];
    const float* b3  = (const float*)d_in[7];
    float* out = (float*)d_out;

    const int N = in_sizes[0] / 64;
    const int E = in_sizes[1] / 2;
    const int* src = ei;
    const int* dst = ei + E;

    const int NBK = cdiv(N, 256);     // 391 buckets of 256 nodes
    const int NBA = cdiv(E, ACHUNK);  // 196 chunks
    const int nmat = NBK * NBA;       // 76636 scan elements
    const int nb = cdiv(nmat, SCAN_CHUNK);  // 75 <= 256

    // workspace layout
    const size_t Np = (size_t)((N + 63) / 64) * 64;
    char* p = (char*)d_ws;
    int*      counts_t = (int*)p;      p += (size_t)nmat * sizeof(int);
    int*      offsets  = (int*)p;      p += (size_t)nmat * sizeof(int);
    int*      bsum     = (int*)p;      p += 1024 * sizeof(int);
    int*      row_start= (int*)p;      p += (Np + 64) * sizeof(int);
    float*    dis      = (float*)p;    p += Np * sizeof(float);
    unsigned* bucketed = (unsigned*)p; p += (size_t)E * sizeof(unsigned);
    int*      csr_src  = (int*)p;      p += (size_t)E * sizeof(int);
    _Float16* bufA     = (_Float16*)p; p += Np * 64 * sizeof(_Float16);
    _Float16* bufB     = (_Float16*)p; p += Np * 64 * sizeof(_Float16);
    (void)ws_size;

    const int B = 256;

    // ---- cooperative grid sizing: query once, cache (host-only, capture-safe)
    static int coop_grid = -1;
    if (coop_grid < 0) {
        int dev = 0;
        (void)hipGetDevice(&dev);
        int ncu = 0;
        (void)hipDeviceGetAttribute(&ncu, hipDeviceAttributeMultiprocessorCount, dev);
        int maxb = 0;
        (void)hipOccupancyMaxActiveBlocksPerMultiprocessor(
            &maxb, (const void*)k_csr_gemm, B, 0);
        long g = (long)maxb * (long)ncu;
        if (g > 1024) g = 1024;
        coop_grid = (int)g;   // 0 => fallback
    }

    if (coop_grid >= 64) {
        const int* src_a = src;
        const int* dst_a = dst;
        int* counts_a = counts_t;
        int* offsets_a = offsets;
        int* bsum_a = bsum;
        unsigned* bucketed_a = bucketed;
        int* csr_a = csr_src;
        int* rs_a = row_start;
        float* dis_a = dis;
        const float* x_a = x;
        const float* w1_a = W1;
        _Float16* h_a = bufA;
        int nbk_a = NBK, nba_a = NBA, nmat_a = nmat, nb_a = nb, n_a = N, e_a = E;
        void* args[] = {&src_a, &dst_a, &counts_a, &offsets_a, &bsum_a,
                        &bucketed_a, &csr_a, &rs_a, &dis_a, &x_a, &w1_a, &h_a,
                        &nbk_a, &nba_a, &nmat_a, &nb_a, &n_a, &e_a};
        hipLaunchCooperativeKernel((void*)k_csr_gemm, dim3(coop_grid), dim3(B),
                                   args, 0, stream);
    } else {
        // fallback: proven separate-kernel pipeline
        k_bucket_hist<<<NBA, B, 0, stream>>>(dst, counts_t, NBK, NBA, E);
        k_scan_partial<<<nb, B, 0, stream>>>(counts_t, bsum, nmat);
        k_scan_final<<<nb, B, 0, stream>>>(counts_t, bsum, offsets, nb, nmat);
        k_bucket_scatter<<<NBA, B, 0, stream>>>(src, dst, offsets, bucketed, NBK, NBA, E);
        k_bucket_build<<<NBK, B, 0, stream>>>(bucketed, offsets, csr_src, row_start, dis,
                                              NBK, NBA, N, E);
        k_gemm_f<64, 64><<<cdiv(N, 32), B, 0, stream>>>(x, W1, dis, bufA, N);
    }

    // ---- fused: agg(h1)+relu -> gemm W2 -> h2 (bufB) ----
    k_fused_agg_gemm<64><<<cdiv(N, 32), B, 0, stream>>>(
        bufA, dis, row_start, csr_src, b1, W2, bufB, N);
    // ---- fused: agg(h2)+relu -> gemm W3 -> h3 (bufA, 32-dim) ----
    k_fused_agg_gemm<32><<<cdiv(N, 32), B, 0, stream>>>(
        bufB, dis, row_start, csr_src, b2, W3, bufA, N);
    // ---- final aggregate: agg(h3) + b3 -> out (fp32) ----
    k_aggregate32<<<cdiv(cdiv(N, 16) * 64, B), B, 0, stream>>>(
        bufA, dis, row_start, csr_src, b3, out, N);
}

// Round 5
// 417.866 us; speedup vs baseline: 1.6913x; 1.6913x over previous
//
#include <hip/hip_runtime.h>

// GCN: 3 layers, dims 64->64->64->32, N=100000 nodes, E=1600000 edges.
// Round 15 (direct-atomic CSR build; coop reverted):
//  - R14: cooperative grid.sync costs ~100us each on 8-XCD gfx950 (device-
//    scope fence = L2 wb-inv + global spin; 604us kernel, VALU 1.5%). Coop
//    mega-kernel abandoned.
//  - R12: scattered 4B writes are ~neutral -> the old 3-pass, 2-LDS-sort CSR
//    build (38MB edge traffic) is overkill. Replace with direct build using
//    device-scope atomics (executed at memory-side LLC, near-BW):
//      memset(deg) -> k_deg (deg[dst]++) -> scan(N) -> k_scatter_direct
//      (csr_src[atomicAdd(cursor[d])]=src). 25.6MB edge traffic, no LDS sort.
//    Row-internal edge order becomes arbitrary: segment-sum is order-indep
//    within fp32 tolerance (absmax 0.0039 << thr 0.0155).
//  - Gather kernels unchanged (R11 form, ~2.9TB/s random-gather ceiling,
//    FETCH within 1.15x of the random-access model floor).

typedef __attribute__((ext_vector_type(8))) _Float16 half8;
typedef __attribute__((ext_vector_type(4))) _Float16 half4;

static inline int cdiv(int a, int b) { return (a + b - 1) / b; }

#define SCAN_CHUNK 1024

// ---- degree count: deg[dst[e]]++ (deg pre-zeroed by memsetAsync)
__global__ __launch_bounds__(256)
void k_deg(const int* __restrict__ dst, int* __restrict__ deg, int E) {
    int t = threadIdx.x;
    int base = blockIdx.x * 1024;
#pragma unroll
    for (int j = 0; j < 4; ++j) {
        int e = base + j * 256 + t;
        if (e < E) atomicAdd(&deg[dst[e]], 1);
    }
}

// ---- scan partial over deg[0..n): per-block sums
__global__ __launch_bounds__(256)
void k_scan_partial(const int* __restrict__ a, int* __restrict__ bsum, int n) {
    __shared__ int red[256];
    int t = threadIdx.x, b = blockIdx.x;
    int base = b * SCAN_CHUNK + t * 4;
    int s = 0;
#pragma unroll
    for (int j = 0; j < 4; ++j) { int i = base + j; if (i < n) s += a[i]; }
    red[t] = s;
    __syncthreads();
    for (int off = 128; off > 0; off >>= 1) {
        if (t < off) red[t] += red[t + off];
        __syncthreads();
    }
    if (t == 0) bsum[b] = red[0];
}

// ---- scan final: row_start (excl scan), cursor copy, dis = rsqrt(1+deg).
// nb <= 256. Every block redundantly scans bsum in LDS, picks its base.
__global__ __launch_bounds__(256)
void k_scan_final(const int* __restrict__ deg, const int* __restrict__ bsum,
                  int* __restrict__ row_start, int* __restrict__ cursor,
                  float* __restrict__ dis, int nb, int n, int E) {
    __shared__ int sb[256];
    __shared__ int sh[256];
    int t = threadIdx.x, bk = blockIdx.x;
    sb[t] = (t < nb) ? bsum[t] : 0;
    __syncthreads();
    for (int off = 1; off < 256; off <<= 1) {
        int u = (t >= off) ? sb[t - off] : 0;
        __syncthreads();
        sb[t] += u;
        __syncthreads();
    }
    int bbase = (bk == 0) ? 0 : sb[bk - 1];
    int base = bk * SCAN_CHUNK + t * 4;
    int v[4];
    int s = 0;
#pragma unroll
    for (int j = 0; j < 4; ++j) {
        int i = base + j;
        v[j] = (i < n) ? deg[i] : 0;
        s += v[j];
    }
    sh[t] = s;
    __syncthreads();
    for (int off = 1; off < 256; off <<= 1) {
        int u = (t >= off) ? sh[t - off] : 0;
        __syncthreads();
        sh[t] += u;
        __syncthreads();
    }
    int run = sh[t] - s + bbase;
#pragma unroll
    for (int j = 0; j < 4; ++j) {
        int i = base + j;
        if (i < n) {
            row_start[i] = run;
            cursor[i] = run;
            dis[i] = rsqrtf(1.0f + (float)v[j]);
            if (i == n - 1) row_start[n] = run + v[j];   // == E
            run += v[j];
        }
    }
}

// ---- direct scatter: csr_src[atomicAdd(cursor[dst])] = src
__global__ __launch_bounds__(256)
void k_scatter_direct(const int* __restrict__ src, const int* __restrict__ dst,
                      int* __restrict__ cursor, int* __restrict__ csr_src, int E) {
    int t = threadIdx.x;
    int base = blockIdx.x * 1024;
#pragma unroll
    for (int j = 0; j < 4; ++j) {
        int e = base + j * 256 + t;
        if (e < E) {
            int d = dst[e];
            int s = src[e];
            int pos = atomicAdd(&cursor[d], 1);
            csr_src[pos] = s;
        }
    }
}

// ---- fp32-input GEMM (layer 1): H = fp16((X@W) * dis[row]), 8 outs/thread
template <int K, int M>
__global__ void k_gemm_f(const float* __restrict__ X, const float* __restrict__ W,
                         const float* __restrict__ dis, _Float16* __restrict__ H, int n) {
    constexpr int TPR = M / 8;
    constexpr int ROWS = 256 / TPR;
    constexpr int KP = K + 1;
    __shared__ float Ws[K * M];
    __shared__ float Xs[ROWS * KP];
    int tid = threadIdx.x;
    for (int idx = tid; idx < K * M / 4; idx += 256)
        ((float4*)Ws)[idx] = ((const float4*)W)[idx];
    int row0 = blockIdx.x * ROWS;
    for (int idx = tid; idx < ROWS * (K / 4); idx += 256) {
        int r = idx / (K / 4), kq = idx % (K / 4);
        int row = row0 + r;
        float4 vv = (row < n) ? ((const float4*)X)[(size_t)row * (K / 4) + kq]
                              : make_float4(0.f, 0.f, 0.f, 0.f);
        Xs[r * KP + kq * 4 + 0] = vv.x;
        Xs[r * KP + kq * 4 + 1] = vv.y;
        Xs[r * KP + kq * 4 + 2] = vv.z;
        Xs[r * KP + kq * 4 + 3] = vv.w;
    }
    __syncthreads();
    int r = tid / TPR, c0 = (tid % TPR) * 8;
    int row = row0 + r;
    if (row >= n) return;
    float4 a0 = make_float4(0.f, 0.f, 0.f, 0.f);
    float4 a1 = make_float4(0.f, 0.f, 0.f, 0.f);
#pragma unroll
    for (int k = 0; k < K; ++k) {
        float xv = Xs[r * KP + k];
        float4 w0 = ((const float4*)Ws)[(k * M + c0) / 4];
        float4 w1 = ((const float4*)Ws)[(k * M + c0) / 4 + 1];
        a0.x = fmaf(xv, w0.x, a0.x);
        a0.y = fmaf(xv, w0.y, a0.y);
        a0.z = fmaf(xv, w0.z, a0.z);
        a0.w = fmaf(xv, w0.w, a0.w);
        a1.x = fmaf(xv, w1.x, a1.x);
        a1.y = fmaf(xv, w1.y, a1.y);
        a1.z = fmaf(xv, w1.z, a1.z);
        a1.w = fmaf(xv, w1.w, a1.w);
    }
    float dn = dis[row];
    half8 hv;
    hv[0] = (_Float16)(a0.x * dn);
    hv[1] = (_Float16)(a0.y * dn);
    hv[2] = (_Float16)(a0.z * dn);
    hv[3] = (_Float16)(a0.w * dn);
    hv[4] = (_Float16)(a1.x * dn);
    hv[5] = (_Float16)(a1.y * dn);
    hv[6] = (_Float16)(a1.z * dn);
    hv[7] = (_Float16)(a1.w * dn);
    ((half8*)H)[(size_t)row * (M / 8) + c0 / 8] = hv;
}

// ---- FUSED: aggregate(64) [+relu] -> LDS -> GEMM(64 x MOUT) -> h' fp16.
// 32 nodes per block (4 waves x 8 nodes, lane-per-8-features, 8-edge unroll).
// W staged as fp16 in LDS, fp32 math.
template <int MOUT>
__global__ __launch_bounds__(256, 8)
void k_fused_agg_gemm(const _Float16* __restrict__ h, const float* __restrict__ dis,
                      const int* __restrict__ row_start, const int* __restrict__ csr_src,
                      const float* __restrict__ bagg, const float* __restrict__ W,
                      _Float16* __restrict__ H, int n) {
    constexpr int K = 64, KP = K + 1;
    __shared__ __align__(16) _Float16 Ws[K * MOUT];
    __shared__ float Xs[32 * KP];
    int tid = threadIdx.x;
    for (int idx = tid; idx < K * MOUT / 4; idx += 256) {
        float4 wv = ((const float4*)W)[idx];
        half4 h4;
        h4[0] = (_Float16)wv.x;
        h4[1] = (_Float16)wv.y;
        h4[2] = (_Float16)wv.z;
        h4[3] = (_Float16)wv.w;
        ((half4*)Ws)[idx] = h4;
    }

    int wave = tid >> 6, lane = tid & 63;
    int sub = lane >> 3, fl = lane & 7;
    int node0 = blockIdx.x * 32;
    int node = node0 + wave * 8 + sub;
    if (node < n) {
        const half8* h8 = (const half8*)h;
        float acc[8];
#pragma unroll
        for (int j = 0; j < 8; ++j) acc[j] = 0.f;
        int e = row_start[node], e1 = row_start[node + 1];
        for (; e + 7 < e1; e += 8) {
            int s0 = csr_src[e], s1 = csr_src[e + 1];
            int s2 = csr_src[e + 2], s3 = csr_src[e + 3];
            int s4 = csr_src[e + 4], s5 = csr_src[e + 5];
            int s6 = csr_src[e + 6], s7 = csr_src[e + 7];
            half8 v0 = h8[(size_t)s0 * 8 + fl];
            half8 v1 = h8[(size_t)s1 * 8 + fl];
            half8 v2 = h8[(size_t)s2 * 8 + fl];
            half8 v3 = h8[(size_t)s3 * 8 + fl];
            half8 v4 = h8[(size_t)s4 * 8 + fl];
            half8 v5 = h8[(size_t)s5 * 8 + fl];
            half8 v6 = h8[(size_t)s6 * 8 + fl];
            half8 v7 = h8[(size_t)s7 * 8 + fl];
#pragma unroll
            for (int j = 0; j < 8; ++j)
                acc[j] += (((float)v0[j] + (float)v1[j]) + ((float)v2[j] + (float)v3[j])) +
                          (((float)v4[j] + (float)v5[j]) + ((float)v6[j] + (float)v7[j]));
        }
        for (; e + 3 < e1; e += 4) {
            int s0 = csr_src[e], s1 = csr_src[e + 1];
            int s2 = csr_src[e + 2], s3 = csr_src[e + 3];
            half8 v0 = h8[(size_t)s0 * 8 + fl];
            half8 v1 = h8[(size_t)s1 * 8 + fl];
            half8 v2 = h8[(size_t)s2 * 8 + fl];
            half8 v3 = h8[(size_t)s3 * 8 + fl];
#pragma unroll
            for (int j = 0; j < 8; ++j)
                acc[j] += ((float)v0[j] + (float)v1[j]) + ((float)v2[j] + (float)v3[j]);
        }
        for (; e < e1; ++e) {
            int s0 = csr_src[e];
            half8 v0 = h8[(size_t)s0 * 8 + fl];
#pragma unroll
            for (int j = 0; j < 8; ++j) acc[j] += (float)v0[j];
        }
        float dn = dis[node];
        half8 hv = h8[(size_t)node * 8 + fl];
        float4 b0 = ((const float4*)bagg)[fl * 2];
        float4 b1 = ((const float4*)bagg)[fl * 2 + 1];
        int rrow = wave * 8 + sub;
        float* xp = &Xs[rrow * KP + fl * 8];
        xp[0] = fmaxf((acc[0] + (float)hv[0]) * dn + b0.x, 0.f);
        xp[1] = fmaxf((acc[1] + (float)hv[1]) * dn + b0.y, 0.f);
        xp[2] = fmaxf((acc[2] + (float)hv[2]) * dn + b0.z, 0.f);
        xp[3] = fmaxf((acc[3] + (float)hv[3]) * dn + b0.w, 0.f);
        xp[4] = fmaxf((acc[4] + (float)hv[4]) * dn + b1.x, 0.f);
        xp[5] = fmaxf((acc[5] + (float)hv[5]) * dn + b1.y, 0.f);
        xp[6] = fmaxf((acc[6] + (float)hv[6]) * dn + b1.z, 0.f);
        xp[7] = fmaxf((acc[7] + (float)hv[7]) * dn + b1.w, 0.f);
    }
    __syncthreads();

    constexpr int TPR = 8;
    constexpr int CPT = MOUT / TPR;   // 8 (MOUT=64) or 4 (MOUT=32)
    int r = tid / TPR, c0 = (tid % TPR) * CPT;
    int row = node0 + r;
    if (row >= n) return;
    float4 a0 = make_float4(0.f, 0.f, 0.f, 0.f);
    float4 a1 = make_float4(0.f, 0.f, 0.f, 0.f);
#pragma unroll
    for (int k = 0; k < K; ++k) {
        float xv = Xs[r * KP + k];
        if constexpr (CPT == 8) {
            half8 w = ((const half8*)Ws)[(k * MOUT + c0) / 8];
            a0.x = fmaf(xv, (float)w[0], a0.x);
            a0.y = fmaf(xv, (float)w[1], a0.y);
            a0.z = fmaf(xv, (float)w[2], a0.z);
            a0.w = fmaf(xv, (float)w[3], a0.w);
            a1.x = fmaf(xv, (float)w[4], a1.x);
            a1.y = fmaf(xv, (float)w[5], a1.y);
            a1.z = fmaf(xv, (float)w[6], a1.z);
            a1.w = fmaf(xv, (float)w[7], a1.w);
        } else {
            half4 w = ((const half4*)Ws)[(k * MOUT + c0) / 4];
            a0.x = fmaf(xv, (float)w[0], a0.x);
            a0.y = fmaf(xv, (float)w[1], a0.y);
            a0.z = fmaf(xv, (float)w[2], a0.z);
            a0.w = fmaf(xv, (float)w[3], a0.w);
        }
    }
    float dn = dis[row];
    if constexpr (CPT == 8) {
        half8 hv;
        hv[0] = (_Float16)(a0.x * dn);
        hv[1] = (_Float16)(a0.y * dn);
        hv[2] = (_Float16)(a0.z * dn);
        hv[3] = (_Float16)(a0.w * dn);
        hv[4] = (_Float16)(a1.x * dn);
        hv[5] = (_Float16)(a1.y * dn);
        hv[6] = (_Float16)(a1.z * dn);
        hv[7] = (_Float16)(a1.w * dn);
        ((half8*)H)[(size_t)row * (MOUT / 8) + c0 / 8] = hv;
    } else {
        half4 hv;
        hv[0] = (_Float16)(a0.x * dn);
        hv[1] = (_Float16)(a0.y * dn);
        hv[2] = (_Float16)(a0.z * dn);
        hv[3] = (_Float16)(a0.w * dn);
        ((half4*)H)[(size_t)row * (MOUT / 4) + c0 / 4] = hv;
    }
}

// ---- final aggregate: M=32, fp32 out, no relu.
__global__ __launch_bounds__(256, 8)
void k_aggregate32(const _Float16* __restrict__ h, const float* __restrict__ dis,
                   const int* __restrict__ row_start, const int* __restrict__ csr_src,
                   const float* __restrict__ b, float* __restrict__ out, int n) {
    constexpr int LPN = 4, NPW = 16;
    int gtid = blockIdx.x * blockDim.x + threadIdx.x;
    int wave = gtid >> 6;
    int lane = threadIdx.x & 63;
    int sub = lane / LPN, fl = lane % LPN;
    int node = wave * NPW + sub;
    if (node >= n) return;
    const half8* h8 = (const half8*)h;
    float acc[8];
#pragma unroll
    for (int j = 0; j < 8; ++j) acc[j] = 0.f;
    int e = row_start[node], e1 = row_start[node + 1];
    for (; e + 7 < e1; e += 8) {
        int s0 = csr_src[e], s1 = csr_src[e + 1];
        int s2 = csr_src[e + 2], s3 = csr_src[e + 3];
        int s4 = csr_src[e + 4], s5 = csr_src[e + 5];
        int s6 = csr_src[e + 6], s7 = csr_src[e + 7];
        half8 v0 = h8[(size_t)s0 * LPN + fl];
        half8 v1 = h8[(size_t)s1 * LPN + fl];
        half8 v2 = h8[(size_t)s2 * LPN + fl];
        half8 v3 = h8[(size_t)s3 * LPN + fl];
        half8 v4 = h8[(size_t)s4 * LPN + fl];
        half8 v5 = h8[(size_t)s5 * LPN + fl];
        half8 v6 = h8[(size_t)s6 * LPN + fl];
        half8 v7 = h8[(size_t)s7 * LPN + fl];
#pragma unroll
        for (int j = 0; j < 8; ++j)
            acc[j] += (((float)v0[j] + (float)v1[j]) + ((float)v2[j] + (float)v3[j])) +
                      (((float)v4[j] + (float)v5[j]) + ((float)v6[j] + (float)v7[j]));
    }
    for (; e + 3 < e1; e += 4) {
        int s0 = csr_src[e], s1 = csr_src[e + 1];
        int s2 = csr_src[e + 2], s3 = csr_src[e + 3];
        half8 v0 = h8[(size_t)s0 * LPN + fl];
        half8 v1 = h8[(size_t)s1 * LPN + fl];
        half8 v2 = h8[(size_t)s2 * LPN + fl];
        half8 v3 = h8[(size_t)s3 * LPN + fl];
#pragma unroll
        for (int j = 0; j < 8; ++j)
            acc[j] += ((float)v0[j] + (float)v1[j]) + ((float)v2[j] + (float)v3[j]);
    }
    for (; e < e1; ++e) {
        int s0 = csr_src[e];
        half8 v0 = h8[(size_t)s0 * LPN + fl];
#pragma unroll
        for (int j = 0; j < 8; ++j) acc[j] += (float)v0[j];
    }
    float dn = dis[node];
    half8 hv = h8[(size_t)node * LPN + fl];
    float4 b0 = ((const float4*)b)[fl * 2];
    float4 b1 = ((const float4*)b)[fl * 2 + 1];
    float4* op = (float4*)(out + ((size_t)node * LPN + fl) * 8);
    op[0] = make_float4((acc[0] + (float)hv[0]) * dn + b0.x,
                        (acc[1] + (float)hv[1]) * dn + b0.y,
                        (acc[2] + (float)hv[2]) * dn + b0.z,
                        (acc[3] + (float)hv[3]) * dn + b0.w);
    op[1] = make_float4((acc[4] + (float)hv[4]) * dn + b1.x,
                        (acc[5] + (float)hv[5]) * dn + b1.y,
                        (acc[6] + (float)hv[6]) * dn + b1.z,
                        (acc[7] + (float)hv[7]) * dn + b1.w);
}

extern "C" void kernel_launch(void* const* d_in, const int* in_sizes, int n_in,
                              void* d_out, int out_size, void* d_ws, size_t ws_size,
                              hipStream_t stream) {
    const float* x   = (const float*)d_in[0];
    const int*   ei  = (const int*)d_in[1];
    const float* W1  = (const float*)d_in[2];
    const float* b1  = (const float*)d_in[3];
    const float* W2  = (const float*)d_in[4];
    const float* b2  = (const float*)d_in[5];
    const float* W3  = (const float*)d_in[6];
    const float* b3  = (const float*)d_in[7];
    float* out = (float*)d_out;

    const int N = in_sizes[0] / 64;
    const int E = in_sizes[1] / 2;
    const int* src = ei;
    const int* dst = ei + E;

    // workspace layout
    const size_t Np = (size_t)((N + 63) / 64) * 64;
    char* p = (char*)d_ws;
    int*      deg      = (int*)p;      p += Np * sizeof(int);
    int*      row_start= (int*)p;      p += (Np + 64) * sizeof(int);
    int*      cursor   = (int*)p;      p += Np * sizeof(int);
    float*    dis      = (float*)p;    p += Np * sizeof(float);
    int*      bsum     = (int*)p;      p += 1024 * sizeof(int);
    int*      csr_src  = (int*)p;      p += (size_t)E * sizeof(int);
    _Float16* bufA     = (_Float16*)p; p += Np * 64 * sizeof(_Float16);
    _Float16* bufB     = (_Float16*)p; p += Np * 64 * sizeof(_Float16);
    (void)ws_size;

    const int B = 256;
    const int nb2 = cdiv(N, SCAN_CHUNK);   // 98 <= 256

    // ---- CSR build: direct, atomics at memory-side LLC ----
    hipMemsetAsync(deg, 0, (size_t)N * sizeof(int), stream);
    k_deg<<<cdiv(E, 1024), B, 0, stream>>>(dst, deg, E);
    k_scan_partial<<<nb2, B, 0, stream>>>(deg, bsum, N);
    k_scan_final<<<nb2, B, 0, stream>>>(deg, bsum, row_start, cursor, dis, nb2, N, E);
    // layer-1 gemm (needs dis, not csr) — runs while csr is still building's turn
    k_gemm_f<64, 64><<<cdiv(N, 32), B, 0, stream>>>(x, W1, dis, bufA, N);
    k_scatter_direct<<<cdiv(E, 1024), B, 0, stream>>>(src, dst, cursor, csr_src, E);

    // ---- fused: agg(h1)+relu -> gemm W2 -> h2 (bufB) ----
    k_fused_agg_gemm<64><<<cdiv(N, 32), B, 0, stream>>>(
        bufA, dis, row_start, csr_src, b1, W2, bufB, N);
    // ---- fused: agg(h2)+relu -> gemm W3 -> h3 (bufA, 32-dim) ----
    k_fused_agg_gemm<32><<<cdiv(N, 32), B, 0, stream>>>(
        bufB, dis, row_start, csr_src, b2, W3, bufA, N);
    // ---- final aggregate: agg(h3) + b3 -> out (fp32) ----
    k_aggregate32<<<cdiv(cdiv(N, 16) * 64, B), B, 0, stream>>>(
        bufA, dis, row_start, csr_src, b3, out, N);
}

// Round 6
// 296.187 us; speedup vs baseline: 2.3861x; 1.4108x over previous
//
#include <hip/hip_runtime.h>

// GCN: 3 layers, dims 64->64->64->32, N=100000 nodes, E=1600000 edges.
// Round 16 (CSR chain occupancy fix; revert R15 atomics):
//  - R15: atomic scatter = 140us (cursor-line ping-pong across XCDs; RMW
//    atomics are XCD-L2-side). R14: grid.sync ~100us each. Both reverted.
//  - Diagnosis for the LDS-sort chain: grid starvation. hist/scatter ran 196
//    blocks, build 391 blocks on 256 CUs (~1 block/CU -> 4 waves/CU on a
//    latency-heavy mix). Fix by grid shape:
//      ACHUNK 8192->2048  => hist/scatter 782 blocks (~3/CU)
//      buckets 256->128   => build 782 blocks (~3/CU), BCAP 4096
//      scan_final extended to nb<=1024 (nmat = 782*782 = 611K)
//  - Gather kernels: exact R11 form (no nontemporal; 63.3us / 160MB fetch =
//    random-gather service ceiling ~2.9TB/s).

typedef __attribute__((ext_vector_type(8))) _Float16 half8;
typedef __attribute__((ext_vector_type(4))) _Float16 half4;

static inline int cdiv(int a, int b) { return (a + b - 1) / b; }

#define ACHUNK 2048   // edges per pass-A block (256 thr x 8)
#define BSHIFT 7      // 128-node buckets
#define BMASK 127
#define MAXNBK 1024   // max buckets (N <= 131072)
#define SCAN_CHUNK 1024
#define BCAP 4096     // bucket capacity for LDS sort (mean 2046)

// ---- pass A1: per-block bucket histogram -> counts_t[bucket*NBA + block]
__global__ __launch_bounds__(256)
void k_bucket_hist(const int* __restrict__ dst, int* __restrict__ counts_t,
                   int NBK, int NBA, int E) {
    __shared__ int cnt[MAXNBK];
    int t = threadIdx.x, b = blockIdx.x;
    for (int i = t; i < NBK; i += 256) cnt[i] = 0;
    __syncthreads();
    int e0 = b * ACHUNK;
#pragma unroll 8
    for (int j = 0; j < ACHUNK / 256; ++j) {
        int e = e0 + j * 256 + t;
        if (e < E) atomicAdd(&cnt[dst[e] >> BSHIFT], 1);
    }
    __syncthreads();
    for (int i = t; i < NBK; i += 256) counts_t[i * NBA + b] = cnt[i];
}

// ---- scan partial: per-block sums of SCAN_CHUNK elements
__global__ __launch_bounds__(256)
void k_scan_partial(const int* __restrict__ a, int* __restrict__ bsum, int n) {
    __shared__ int red[256];
    int t = threadIdx.x, b = blockIdx.x;
    int base = b * SCAN_CHUNK + t * 4;
    int s = 0;
#pragma unroll
    for (int j = 0; j < 4; ++j) { int i = base + j; if (i < n) s += a[i]; }
    red[t] = s;
    __syncthreads();
    for (int off = 128; off > 0; off >>= 1) {
        if (t < off) red[t] += red[t + off];
        __syncthreads();
    }
    if (t == 0) bsum[b] = red[0];
}

// ---- scan final: nb <= 1024. Each thread owns bsum[4t..4t+4); block base is
// broadcast via LDS; then standard chunk scan.
__global__ __launch_bounds__(256)
void k_scan_final(const int* __restrict__ a, const int* __restrict__ bsum,
                  int* __restrict__ out, int nb, int n) {
    __shared__ int sh[256];
    __shared__ int bb;
    int t = threadIdx.x, bk = blockIdx.x;
    // block-sum prefix over up to 1024 entries
    int bv[4];
    int bt = 0;
#pragma unroll
    for (int j = 0; j < 4; ++j) {
        int i = 4 * t + j;
        bv[j] = (i < nb) ? bsum[i] : 0;
        bt += bv[j];
    }
    sh[t] = bt;
    __syncthreads();
    for (int off = 1; off < 256; off <<= 1) {
        int u = (t >= off) ? sh[t - off] : 0;
        __syncthreads();
        sh[t] += u;
        __syncthreads();
    }
    int bexcl = sh[t] - bt;
    if (bk == 0) {
        if (t == 0) bb = 0;
    } else {
        int q = bk - 1;
        if (t == (q >> 2)) {
            int s = bexcl;
#pragma unroll
            for (int j = 0; j < 4; ++j)
                if (j <= (q & 3)) s += bv[j];
            bb = s;
        }
    }
    __syncthreads();
    int bbase = bb;
    __syncthreads();
    // chunk scan
    int base = bk * SCAN_CHUNK + t * 4;
    int v[4];
    int s = 0;
#pragma unroll
    for (int j = 0; j < 4; ++j) {
        int i = base + j;
        v[j] = (i < n) ? a[i] : 0;
        s += v[j];
    }
    sh[t] = s;
    __syncthreads();
    for (int off = 1; off < 256; off <<= 1) {
        int u = (t >= off) ? sh[t - off] : 0;
        __syncthreads();
        sh[t] += u;
        __syncthreads();
    }
    int run = sh[t] - s + bbase;
#pragma unroll
    for (int j = 0; j < 4; ++j) {
        int i = base + j;
        if (i < n) { out[i] = run; run += v[j]; }
    }
}

// ---- pass A3: scatter edges into bucket regions via LDS cursors.
// packed word: src (24 bits) | (dst & 127) << 24.
__global__ __launch_bounds__(256)
void k_bucket_scatter(const int* __restrict__ src, const int* __restrict__ dst,
                      const int* __restrict__ offsets, unsigned* __restrict__ bucketed,
                      int NBK, int NBA, int E) {
    __shared__ int curs[MAXNBK];
    int t = threadIdx.x, b = blockIdx.x;
    for (int i = t; i < NBK; i += 256) curs[i] = offsets[i * NBA + b];
    __syncthreads();
    int e0 = b * ACHUNK;
#pragma unroll 8
    for (int j = 0; j < ACHUNK / 256; ++j) {
        int e = e0 + j * 256 + t;
        if (e < E) {
            int d = dst[e];
            int pos = atomicAdd(&curs[d >> BSHIFT], 1);
            bucketed[pos] = (unsigned)src[e] | ((unsigned)(d & BMASK) << 24);
        }
    }
}

// ---- pass B: one block per 128-node bucket. LDS hist -> scan -> LDS sort ->
// coalesced csr_src write; row_start, dis.
__global__ __launch_bounds__(256)
void k_bucket_build(const unsigned* __restrict__ bucketed,
                    const int* __restrict__ offsets,
                    int* __restrict__ csr_src, int* __restrict__ row_start,
                    float* __restrict__ dis, int NBK, int NBA, int N, int E) {
    __shared__ int cnt[128];
    __shared__ int sc[128];
    __shared__ int srt[BCAP];
    int t = threadIdx.x, k = blockIdx.x;
    int base = offsets[k * NBA];
    int end = (k + 1 < NBK) ? offsets[(k + 1) * NBA] : E;
    if (t < 128) cnt[t] = 0;
    __syncthreads();
    for (int i = base + t; i < end; i += 256)
        atomicAdd(&cnt[bucketed[i] >> 24], 1);
    __syncthreads();
    int c = 0;
    if (t < 128) { c = cnt[t]; sc[t] = c; }
    __syncthreads();
    for (int off = 1; off < 128; off <<= 1) {
        int u = (t >= off && t < 128) ? sc[t - off] : 0;
        __syncthreads();
        if (t < 128) sc[t] += u;
        __syncthreads();
    }
    if (t < 128) {
        int excl = sc[t] - c;
        int node = (k << BSHIFT) + t;
        if (node < N) {
            row_start[node] = base + excl;
            dis[node] = rsqrtf(1.0f + (float)c);
        }
        cnt[t] = excl;  // local cursor
    }
    if (k == 0 && t == 0) row_start[N] = E;
    __syncthreads();
    int m = end - base;
    if (m <= BCAP) {
        for (int i = base + t; i < end; i += 256) {
            unsigned w = bucketed[i];
            int r = atomicAdd(&cnt[w >> 24], 1);
            srt[r] = (int)(w & 0xFFFFFFu);
        }
        __syncthreads();
        for (int idx = t; idx < m; idx += 256)
            csr_src[base + idx] = srt[idx];
    } else {
        // fallback: scattered writes (statistically unreachable)
        for (int i = base + t; i < end; i += 256) {
            unsigned w = bucketed[i];
            int pos = base + atomicAdd(&cnt[w >> 24], 1);
            csr_src[pos] = (int)(w & 0xFFFFFFu);
        }
    }
}

// ---- fp32-input GEMM (layer 1): H = fp16((X@W) * dis[row]), 8 outs/thread
template <int K, int M>
__global__ void k_gemm_f(const float* __restrict__ X, const float* __restrict__ W,
                         const float* __restrict__ dis, _Float16* __restrict__ H, int n) {
    constexpr int TPR = M / 8;
    constexpr int ROWS = 256 / TPR;
    constexpr int KP = K + 1;
    __shared__ float Ws[K * M];
    __shared__ float Xs[ROWS * KP];
    int tid = threadIdx.x;
    for (int idx = tid; idx < K * M / 4; idx += 256)
        ((float4*)Ws)[idx] = ((const float4*)W)[idx];
    int row0 = blockIdx.x * ROWS;
    for (int idx = tid; idx < ROWS * (K / 4); idx += 256) {
        int r = idx / (K / 4), kq = idx % (K / 4);
        int row = row0 + r;
        float4 vv = (row < n) ? ((const float4*)X)[(size_t)row * (K / 4) + kq]
                              : make_float4(0.f, 0.f, 0.f, 0.f);
        Xs[r * KP + kq * 4 + 0] = vv.x;
        Xs[r * KP + kq * 4 + 1] = vv.y;
        Xs[r * KP + kq * 4 + 2] = vv.z;
        Xs[r * KP + kq * 4 + 3] = vv.w;
    }
    __syncthreads();
    int r = tid / TPR, c0 = (tid % TPR) * 8;
    int row = row0 + r;
    if (row >= n) return;
    float4 a0 = make_float4(0.f, 0.f, 0.f, 0.f);
    float4 a1 = make_float4(0.f, 0.f, 0.f, 0.f);
#pragma unroll
    for (int k = 0; k < K; ++k) {
        float xv = Xs[r * KP + k];
        float4 w0 = ((const float4*)Ws)[(k * M + c0) / 4];
        float4 w1 = ((const float4*)Ws)[(k * M + c0) / 4 + 1];
        a0.x = fmaf(xv, w0.x, a0.x);
        a0.y = fmaf(xv, w0.y, a0.y);
        a0.z = fmaf(xv, w0.z, a0.z);
        a0.w = fmaf(xv, w0.w, a0.w);
        a1.x = fmaf(xv, w1.x, a1.x);
        a1.y = fmaf(xv, w1.y, a1.y);
        a1.z = fmaf(xv, w1.z, a1.z);
        a1.w = fmaf(xv, w1.w, a1.w);
    }
    float dn = dis[row];
    half8 hv;
    hv[0] = (_Float16)(a0.x * dn);
    hv[1] = (_Float16)(a0.y * dn);
    hv[2] = (_Float16)(a0.z * dn);
    hv[3] = (_Float16)(a0.w * dn);
    hv[4] = (_Float16)(a1.x * dn);
    hv[5] = (_Float16)(a1.y * dn);
    hv[6] = (_Float16)(a1.z * dn);
    hv[7] = (_Float16)(a1.w * dn);
    ((half8*)H)[(size_t)row * (M / 8) + c0 / 8] = hv;
}

// ---- FUSED: aggregate(64) [+relu] -> LDS -> GEMM(64 x MOUT) -> h' fp16.
// 32 nodes per block (4 waves x 8 nodes, lane-per-8-features, 8-edge unroll).
// W staged as fp16 in LDS, fp32 math.
template <int MOUT>
__global__ __launch_bounds__(256, 8)
void k_fused_agg_gemm(const _Float16* __restrict__ h, const float* __restrict__ dis,
                      const int* __restrict__ row_start, const int* __restrict__ csr_src,
                      const float* __restrict__ bagg, const float* __restrict__ W,
                      _Float16* __restrict__ H, int n) {
    constexpr int K = 64, KP = K + 1;
    __shared__ __align__(16) _Float16 Ws[K * MOUT];
    __shared__ float Xs[32 * KP];
    int tid = threadIdx.x;
    for (int idx = tid; idx < K * MOUT / 4; idx += 256) {
        float4 wv = ((const float4*)W)[idx];
        half4 h4;
        h4[0] = (_Float16)wv.x;
        h4[1] = (_Float16)wv.y;
        h4[2] = (_Float16)wv.z;
        h4[3] = (_Float16)wv.w;
        ((half4*)Ws)[idx] = h4;
    }

    int wave = tid >> 6, lane = tid & 63;
    int sub = lane >> 3, fl = lane & 7;
    int node0 = blockIdx.x * 32;
    int node = node0 + wave * 8 + sub;
    if (node < n) {
        const half8* h8 = (const half8*)h;
        float acc[8];
#pragma unroll
        for (int j = 0; j < 8; ++j) acc[j] = 0.f;
        int e = row_start[node], e1 = row_start[node + 1];
        for (; e + 7 < e1; e += 8) {
            int s0 = csr_src[e], s1 = csr_src[e + 1];
            int s2 = csr_src[e + 2], s3 = csr_src[e + 3];
            int s4 = csr_src[e + 4], s5 = csr_src[e + 5];
            int s6 = csr_src[e + 6], s7 = csr_src[e + 7];
            half8 v0 = h8[(size_t)s0 * 8 + fl];
            half8 v1 = h8[(size_t)s1 * 8 + fl];
            half8 v2 = h8[(size_t)s2 * 8 + fl];
            half8 v3 = h8[(size_t)s3 * 8 + fl];
            half8 v4 = h8[(size_t)s4 * 8 + fl];
            half8 v5 = h8[(size_t)s5 * 8 + fl];
            half8 v6 = h8[(size_t)s6 * 8 + fl];
            half8 v7 = h8[(size_t)s7 * 8 + fl];
#pragma unroll
            for (int j = 0; j < 8; ++j)
                acc[j] += (((float)v0[j] + (float)v1[j]) + ((float)v2[j] + (float)v3[j])) +
                          (((float)v4[j] + (float)v5[j]) + ((float)v6[j] + (float)v7[j]));
        }
        for (; e + 3 < e1; e += 4) {
            int s0 = csr_src[e], s1 = csr_src[e + 1];
            int s2 = csr_src[e + 2], s3 = csr_src[e + 3];
            half8 v0 = h8[(size_t)s0 * 8 + fl];
            half8 v1 = h8[(size_t)s1 * 8 + fl];
            half8 v2 = h8[(size_t)s2 * 8 + fl];
            half8 v3 = h8[(size_t)s3 * 8 + fl];
#pragma unroll
            for (int j = 0; j < 8; ++j)
                acc[j] += ((float)v0[j] + (float)v1[j]) + ((float)v2[j] + (float)v3[j]);
        }
        for (; e < e1; ++e) {
            int s0 = csr_src[e];
            half8 v0 = h8[(size_t)s0 * 8 + fl];
#pragma unroll
            for (int j = 0; j < 8; ++j) acc[j] += (float)v0[j];
        }
        float dn = dis[node];
        half8 hv = h8[(size_t)node * 8 + fl];
        float4 b0 = ((const float4*)bagg)[fl * 2];
        float4 b1 = ((const float4*)bagg)[fl * 2 + 1];
        int rrow = wave * 8 + sub;
        float* xp = &Xs[rrow * KP + fl * 8];
        xp[0] = fmaxf((acc[0] + (float)hv[0]) * dn + b0.x, 0.f);
        xp[1] = fmaxf((acc[1] + (float)hv[1]) * dn + b0.y, 0.f);
        xp[2] = fmaxf((acc[2] + (float)hv[2]) * dn + b0.z, 0.f);
        xp[3] = fmaxf((acc[3] + (float)hv[3]) * dn + b0.w, 0.f);
        xp[4] = fmaxf((acc[4] + (float)hv[4]) * dn + b1.x, 0.f);
        xp[5] = fmaxf((acc[5] + (float)hv[5]) * dn + b1.y, 0.f);
        xp[6] = fmaxf((acc[6] + (float)hv[6]) * dn + b1.z, 0.f);
        xp[7] = fmaxf((acc[7] + (float)hv[7]) * dn + b1.w, 0.f);
    }
    __syncthreads();

    constexpr int TPR = 8;
    constexpr int CPT = MOUT / TPR;   // 8 (MOUT=64) or 4 (MOUT=32)
    int r = tid / TPR, c0 = (tid % TPR) * CPT;
    int row = node0 + r;
    if (row >= n) return;
    float4 a0 = make_float4(0.f, 0.f, 0.f, 0.f);
    float4 a1 = make_float4(0.f, 0.f, 0.f, 0.f);
#pragma unroll
    for (int k = 0; k < K; ++k) {
        float xv = Xs[r * KP + k];
        if constexpr (CPT == 8) {
            half8 w = ((const half8*)Ws)[(k * MOUT + c0) / 8];
            a0.x = fmaf(xv, (float)w[0], a0.x);
            a0.y = fmaf(xv, (float)w[1], a0.y);
            a0.z = fmaf(xv, (float)w[2], a0.z);
            a0.w = fmaf(xv, (float)w[3], a0.w);
            a1.x = fmaf(xv, (float)w[4], a1.x);
            a1.y = fmaf(xv, (float)w[5], a1.y);
            a1.z = fmaf(xv, (float)w[6], a1.z);
            a1.w = fmaf(xv, (float)w[7], a1.w);
        } else {
            half4 w = ((const half4*)Ws)[(k * MOUT + c0) / 4];
            a0.x = fmaf(xv, (float)w[0], a0.x);
            a0.y = fmaf(xv, (float)w[1], a0.y);
            a0.z = fmaf(xv, (float)w[2], a0.z);
            a0.w = fmaf(xv, (float)w[3], a0.w);
        }
    }
    float dn = dis[row];
    if constexpr (CPT == 8) {
        half8 hv;
        hv[0] = (_Float16)(a0.x * dn);
        hv[1] = (_Float16)(a0.y * dn);
        hv[2] = (_Float16)(a0.z * dn);
        hv[3] = (_Float16)(a0.w * dn);
        hv[4] = (_Float16)(a1.x * dn);
        hv[5] = (_Float16)(a1.y * dn);
        hv[6] = (_Float16)(a1.z * dn);
        hv[7] = (_Float16)(a1.w * dn);
        ((half8*)H)[(size_t)row * (MOUT / 8) + c0 / 8] = hv;
    } else {
        half4 hv;
        hv[0] = (_Float16)(a0.x * dn);
        hv[1] = (_Float16)(a0.y * dn);
        hv[2] = (_Float16)(a0.z * dn);
        hv[3] = (_Float16)(a0.w * dn);
        ((half4*)H)[(size_t)row * (MOUT / 4) + c0 / 4] = hv;
    }
}

// ---- final aggregate: M=32, fp32 out, no relu.
__global__ __launch_bounds__(256, 8)
void k_aggregate32(const _Float16* __restrict__ h, const float* __restrict__ dis,
                   const int* __restrict__ row_start, const int* __restrict__ csr_src,
                   const float* __restrict__ b, float* __restrict__ out, int n) {
    constexpr int LPN = 4, NPW = 16;
    int gtid = blockIdx.x * blockDim.x + threadIdx.x;
    int wave = gtid >> 6;
    int lane = threadIdx.x & 63;
    int sub = lane / LPN, fl = lane % LPN;
    int node = wave * NPW + sub;
    if (node >= n) return;
    const half8* h8 = (const half8*)h;
    float acc[8];
#pragma unroll
    for (int j = 0; j < 8; ++j) acc[j] = 0.f;
    int e = row_start[node], e1 = row_start[node + 1];
    for (; e + 7 < e1; e += 8) {
        int s0 = csr_src[e], s1 = csr_src[e + 1];
        int s2 = csr_src[e + 2], s3 = csr_src[e + 3];
        int s4 = csr_src[e + 4], s5 = csr_src[e + 5];
        int s6 = csr_src[e + 6], s7 = csr_src[e + 7];
        half8 v0 = h8[(size_t)s0 * LPN + fl];
        half8 v1 = h8[(size_t)s1 * LPN + fl];
        half8 v2 = h8[(size_t)s2 * LPN + fl];
        half8 v3 = h8[(size_t)s3 * LPN + fl];
        half8 v4 = h8[(size_t)s4 * LPN + fl];
        half8 v5 = h8[(size_t)s5 * LPN + fl];
        half8 v6 = h8[(size_t)s6 * LPN + fl];
        half8 v7 = h8[(size_t)s7 * LPN + fl];
#pragma unroll
        for (int j = 0; j < 8; ++j)
            acc[j] += (((float)v0[j] + (float)v1[j]) + ((float)v2[j] + (float)v3[j])) +
                      (((float)v4[j] + (float)v5[j]) + ((float)v6[j] + (float)v7[j]));
    }
    for (; e + 3 < e1; e += 4) {
        int s0 = csr_src[e], s1 = csr_src[e + 1];
        int s2 = csr_src[e + 2], s3 = csr_src[e + 3];
        half8 v0 = h8[(size_t)s0 * LPN + fl];
        half8 v1 = h8[(size_t)s1 * LPN + fl];
        half8 v2 = h8[(size_t)s2 * LPN + fl];
        half8 v3 = h8[(size_t)s3 * LPN + fl];
#pragma unroll
        for (int j = 0; j < 8; ++j)
            acc[j] += ((float)v0[j] + (float)v1[j]) + ((float)v2[j] + (float)v3[j]);
    }
    for (; e < e1; ++e) {
        int s0 = csr_src[e];
        half8 v0 = h8[(size_t)s0 * LPN + fl];
#pragma unroll
        for (int j = 0; j < 8; ++j) acc[j] += (float)v0[j];
    }
    float dn = dis[node];
    half8 hv = h8[(size_t)node * LPN + fl];
    float4 b0 = ((const float4*)b)[fl * 2];
    float4 b1 = ((const float4*)b)[fl * 2 + 1];
    float4* op = (float4*)(out + ((size_t)node * LPN + fl) * 8);
    op[0] = make_float4((acc[0] + (float)hv[0]) * dn + b0.x,
                        (acc[1] + (float)hv[1]) * dn + b0.y,
                        (acc[2] + (float)hv[2]) * dn + b0.z,
                        (acc[3] + (float)hv[3]) * dn + b0.w);
    op[1] = make_float4((acc[4] + (float)hv[4]) * dn + b1.x,
                        (acc[5] + (float)hv[5]) * dn + b1.y,
                        (acc[6] + (float)hv[6]) * dn + b1.z,
                        (acc[7] + (float)hv[7]) * dn + b1.w);
}

extern "C" void kernel_launch(void* const* d_in, const int* in_sizes, int n_in,
                              void* d_out, int out_size, void* d_ws, size_t ws_size,
                              hipStream_t stream) {
    const float* x   = (const float*)d_in[0];
    const int*   ei  = (const int*)d_in[1];
    const float* W1  = (const float*)d_in[2];
    const float* b1  = (const float*)d_in[3];
    const float* W2  = (const float*)d_in[4];
    const float* b2  = (const float*)d_in[5];
    const float* W3  = (const float*)d_in[6];
    const float* b3  = (const float*)d_in[7];
    float* out = (float*)d_out;

    const int N = in_sizes[0] / 64;
    const int E = in_sizes[1] / 2;
    const int* src = ei;
    const int* dst = ei + E;

    const int NBK = cdiv(N, 128);           // 782 buckets of 128 nodes
    const int NBA = cdiv(E, ACHUNK);        // 782 chunks
    const int nmat = NBK * NBA;             // ~611K scan elements
    const int nb = cdiv(nmat, SCAN_CHUNK);  // ~598 <= 1024

    // workspace layout
    const size_t Np = (size_t)((N + 63) / 64) * 64;
    char* p = (char*)d_ws;
    int*      counts_t = (int*)p;      p += (size_t)nmat * sizeof(int);
    int*      offsets  = (int*)p;      p += (size_t)nmat * sizeof(int);
    int*      bsum     = (int*)p;      p += 1024 * sizeof(int);
    int*      row_start= (int*)p;      p += (Np + 64) * sizeof(int);
    float*    dis      = (float*)p;    p += Np * sizeof(float);
    unsigned* bucketed = (unsigned*)p; p += (size_t)E * sizeof(unsigned);
    int*      csr_src  = (int*)p;      p += (size_t)E * sizeof(int);
    _Float16* bufA     = (_Float16*)p; p += Np * 64 * sizeof(_Float16);
    _Float16* bufB     = (_Float16*)p; p += Np * 64 * sizeof(_Float16);
    (void)ws_size;

    const int B = 256;

    // ---- CSR build: LDS counting sort, no global atomics ----
    k_bucket_hist<<<NBA, B, 0, stream>>>(dst, counts_t, NBK, NBA, E);
    k_scan_partial<<<nb, B, 0, stream>>>(counts_t, bsum, nmat);
    k_scan_final<<<nb, B, 0, stream>>>(counts_t, bsum, offsets, nb, nmat);
    k_bucket_scatter<<<NBA, B, 0, stream>>>(src, dst, offsets, bucketed, NBK, NBA, E);
    k_bucket_build<<<NBK, B, 0, stream>>>(bucketed, offsets, csr_src, row_start, dis,
                                          NBK, NBA, N, E);

    // ---- layer 1 gemm: x(64) @ W1 -> h1 (bufA) ----
    k_gemm_f<64, 64><<<cdiv(N, 32), B, 0, stream>>>(x, W1, dis, bufA, N);
    // ---- fused: agg(h1)+relu -> gemm W2 -> h2 (bufB) ----
    k_fused_agg_gemm<64><<<cdiv(N, 32), B, 0, stream>>>(
        bufA, dis, row_start, csr_src, b1, W2, bufB, N);
    // ---- fused: agg(h2)+relu -> gemm W3 -> h3 (bufA, 32-dim) ----
    k_fused_agg_gemm<32><<<cdiv(N, 32), B, 0, stream>>>(
        bufB, dis, row_start, csr_src, b2, W3, bufA, N);
    // ---- final aggregate: agg(h3) + b3 -> out (fp32) ----
    k_aggregate32<<<cdiv(cdiv(N, 16) * 64, B), B, 0, stream>>>(
        bufA, dis, row_start, csr_src, b3, out, N);
}